// Round 11
// baseline (465.302 us; speedup 1.0000x reference)
//
#include <hip/hip_runtime.h>
#include <hip/hip_bf16.h>
#include <stdint.h>

typedef __bf16 bf16;
typedef __attribute__((ext_vector_type(8))) __bf16 bf16x8;
typedef __attribute__((ext_vector_type(4))) __bf16 bf16x4;
typedef __attribute__((ext_vector_type(4))) float f32x4;
typedef __attribute__((ext_vector_type(16))) float f32x16;
typedef __attribute__((ext_vector_type(4))) unsigned int uint4v;

#define S_LEN 2048
#define HDIM  4096
#define NQH   32
#define NKVH  8
#define DHEAD 128
#define QKVN  6144   /* 4096 Q + 1024 K + 1024 V */
#define KOFF  4096
#define VOFF  5120
#define NSPLIT 4

__device__ __forceinline__ void gload_lds16(const bf16* g, bf16* l) {
  __builtin_amdgcn_global_load_lds(
      (const __attribute__((address_space(1))) unsigned int*)g,
      (__attribute__((address_space(3))) unsigned int*)l, 16, 0, 0);
}

// ---------------------------------------------------------------- f32 -> bf16
__global__ __launch_bounds__(256) void cvt_f32_bf16(const float* __restrict__ in,
                                                    bf16* __restrict__ out, int n4) {
  int i = blockIdx.x * 256 + threadIdx.x;
  if (i >= n4) return;
  float4 v = ((const float4*)in)[i];
  bf16x4 ov = {(bf16)v.x, (bf16)v.y, (bf16)v.z, (bf16)v.w};
  *(bf16x4*)&out[(size_t)i * 4] = ov;
}

// ---------------------------------------------------------------- RoPE table
__global__ __launch_bounds__(256) void rope_table(const int* __restrict__ pos,
                                                  float* __restrict__ tab) {
  int idx = blockIdx.x * 256 + threadIdx.x;  // 2048*64
  int i = idx & 63, s = idx >> 6;
  float p = (float)pos[s];
  float invf = powf(10000.0f, -(float)i * (1.0f / 64.0f));
  float ang = p * invf;
  tab[idx * 2]     = cosf(ang);
  tab[idx * 2 + 1] = sinf(ang);
}

// ---------------------------------------------------------------- RoPE apply (in-place on Q,K cols of QKV)
__global__ __launch_bounds__(256) void rope_apply(bf16* __restrict__ QKV,
                                                  const float* __restrict__ tab) {
  int idx = blockIdx.x * 256 + threadIdx.x;  // 2048*40*64
  int dp = idx & 63;
  int t = idx >> 6;
  int head = t % 40;          // 0..31 = Q heads, 32..39 = K heads
  int s = t / 40;
  float c  = tab[(s * 64 + dp) * 2];
  float sn = tab[(s * 64 + dp) * 2 + 1];
  size_t base = (size_t)s * QKVN + head * DHEAD;
  float x0 = (float)QKV[base + dp];
  float x1 = (float)QKV[base + 64 + dp];
  QKV[base + dp]      = (bf16)(x0 * c - x1 * sn);
  QKV[base + 64 + dp] = (bf16)(x1 * c + x0 * sn);
}

// ---------------------------------------------------------------- V transpose: QKV V-cols -> Vt[kvh*128+d][s]
__global__ __launch_bounds__(256) void transpose_v(const bf16* __restrict__ QKV,
                                                   bf16* __restrict__ Vt) {
  __shared__ bf16 t[64][72];
  int tid = threadIdx.x;
  int bs = blockIdx.x * 64, bc = blockIdx.y * 64;
  int sl = tid >> 3, cb = (tid & 7) * 8;
#pragma unroll
  for (int ss = 0; ss < 64; ss += 32) {
    int s = sl + ss;
    *(bf16x8*)&t[s][cb] = *(const bf16x8*)&QKV[(size_t)(bs + s) * QKVN + VOFF + bc + cb];
  }
  __syncthreads();
  int cl = tid >> 3, sb = (tid & 7) * 8;
#pragma unroll
  for (int cc = 0; cc < 64; cc += 32) {
    int c = cl + cc;
    bf16x8 v;
#pragma unroll
    for (int k = 0; k < 8; ++k) v[k] = t[sb + k][c];
    *(bf16x8*)&Vt[(size_t)(bc + c) * S_LEN + bs + sb] = v;
  }
}

// ---------------------------------------------------------------- GEMM, phase-split quad-buffer: C[M,N] = A[M,K]*B[N,K]^T
// BK=32, 4 LDS slots per matrix (iteration t computes slot t&3, stages tile
// t+2 into slot (t+2)&3 -- always disjoint from slots being read/landed).
// End-of-iteration: counted s_waitcnt vmcnt(LA+LB) (T4: tile t+1 landed,
// t+2 stays in flight across the raw barrier; never drains to 0 in steady
// state) -- the round-8 attention pattern that beat the drain-to-0 pathology.
// Two phases per K-tile: {ds_read || stage -> barrier -> lgkmcnt(0) ->
// setprio(1) MFMA setprio(0) -> barrier} (T2+T3+T5 fine interleave, m196).
// Swizzle: chunk c ^ ((row^(row>>2))&3), both-sides (G21); max 2-way (free).
// Compact per-XCD 2D tile ownership (XR x XC tiles per XCD).
template <typename OutT, int BM, int BN, int WM, int WN, int XR, int XC, int XCX>
__global__ __launch_bounds__(512, 2) void gemm8p(const bf16* __restrict__ A,
                                                 const bf16* __restrict__ B,
                                                 OutT* __restrict__ C,
                                                 int M, int N, int K) {
  constexpr int PM = BM / WM, PN = BN / WN;
  constexpr int MI = PM / 16, NJ = PN / 16;
  constexpr int MIH = MI / 2;
  constexpr int LA = BM / 128, LB = BN / 128;
  __shared__ bf16 Abuf[4][BM * 32];
  __shared__ bf16 Bbuf[4][BN * 32];
  const int tid = threadIdx.x;
  const int w = tid >> 6, lane = tid & 63;
  const int r = lane & 15, g = lane >> 4;
  const int wr = w / WN, wc = w % WN;
  const int id = blockIdx.x;
  const int xcd = id & 7, o = id >> 3;       // dispatch round-robins id%8 -> XCD
  const int by = (xcd / XCX) * XR + o / XC;
  const int bx = (xcd % XCX) * XC + o % XC;
  const int bm = by * BM, bn = bx * BN;

  f32x4 acc[MI][NJ];
#pragma unroll
  for (int mi = 0; mi < MI; ++mi)
#pragma unroll
    for (int nj = 0; nj < NJ; ++nj) acc[mi][nj] = (f32x4){0.f, 0.f, 0.f, 0.f};

  auto stageA = [&](int slot, int k0) {
#pragma unroll
    for (int j = 0; j < LA; ++j) {
      int cid = (j * 8 + w) * 64 + lane;
      int row = cid >> 2, c = cid & 3;
      int sw = (row ^ (row >> 2)) & 3;
      gload_lds16(&A[(size_t)(bm + row) * K + k0 + ((c ^ sw) << 3)],
                  &Abuf[slot][(j * 8 + w) * 512]);
    }
  };
  auto stageB = [&](int slot, int k0) {
#pragma unroll
    for (int j = 0; j < LB; ++j) {
      int cid = (j * 8 + w) * 64 + lane;
      int row = cid >> 2, c = cid & 3;
      int sw = (row ^ (row >> 2)) & 3;
      gload_lds16(&B[(size_t)(bn + row) * K + k0 + ((c ^ sw) << 3)],
                  &Bbuf[slot][(j * 8 + w) * 512]);
    }
  };

  const int NT = K >> 5;
  // prologue: stage tiles 0 and 1; wait only for tile 0 (counted)
  stageA(0, 0);  stageB(0, 0);
  stageA(1, 32); stageB(1, 32);
  if constexpr (LA + LB == 4) asm volatile("s_waitcnt vmcnt(4)" ::: "memory");
  else                        asm volatile("s_waitcnt vmcnt(3)" ::: "memory");
  __builtin_amdgcn_s_barrier();
  asm volatile("" ::: "memory");

  for (int t = 0; t < NT; ++t) {
    const int slot = t & 3;
    const bf16* Ac = Abuf[slot];
    const bf16* Bc = Bbuf[slot];
    const bool pre = (t + 2 < NT);
    if (pre) { stageA((t + 2) & 3, (t + 2) << 5); stageB((t + 2) & 3, (t + 2) << 5); }

    bf16x8 af[MIH], af2[MIH], bfr[NJ];
    // ---- phase 0: A lower half + all B; MFMA lower half
#pragma unroll
    for (int mi = 0; mi < MIH; ++mi) {
      int row = wr * PM + mi * 16 + r;
      int sw = (row ^ (row >> 2)) & 3;
      af[mi] = *(const bf16x8*)&Ac[row * 32 + ((g ^ sw) << 3)];
    }
#pragma unroll
    for (int nj = 0; nj < NJ; ++nj) {
      int row = wc * PN + nj * 16 + r;
      int sw = (row ^ (row >> 2)) & 3;
      bfr[nj] = *(const bf16x8*)&Bc[row * 32 + ((g ^ sw) << 3)];
    }
    __builtin_amdgcn_s_barrier();
    asm volatile("s_waitcnt lgkmcnt(0)" ::: "memory");
    __builtin_amdgcn_s_setprio(1);
#pragma unroll
    for (int mi = 0; mi < MIH; ++mi)
#pragma unroll
      for (int nj = 0; nj < NJ; ++nj)
        acc[mi][nj] = __builtin_amdgcn_mfma_f32_16x16x32_bf16(af[mi], bfr[nj],
                                                              acc[mi][nj], 0, 0, 0);
    __builtin_amdgcn_s_setprio(0);
    __builtin_amdgcn_s_barrier();
    asm volatile("" ::: "memory");

    // ---- phase 1: A upper half (B reused); MFMA upper half
#pragma unroll
    for (int mi = 0; mi < MIH; ++mi) {
      int row = wr * PM + (MIH + mi) * 16 + r;
      int sw = (row ^ (row >> 2)) & 3;
      af2[mi] = *(const bf16x8*)&Ac[row * 32 + ((g ^ sw) << 3)];
    }
    __builtin_amdgcn_s_barrier();
    asm volatile("s_waitcnt lgkmcnt(0)" ::: "memory");
    __builtin_amdgcn_s_setprio(1);
#pragma unroll
    for (int mi = 0; mi < MIH; ++mi)
#pragma unroll
      for (int nj = 0; nj < NJ; ++nj)
        acc[MIH + mi][nj] = __builtin_amdgcn_mfma_f32_16x16x32_bf16(af2[mi], bfr[nj],
                                                                    acc[MIH + mi][nj], 0, 0, 0);
    __builtin_amdgcn_s_setprio(0);

    // ---- iteration end: counted wait (t+1 landed; t+2 in flight) + barrier
    if (pre) {
      if constexpr (LA + LB == 4) asm volatile("s_waitcnt vmcnt(4)" ::: "memory");
      else                        asm volatile("s_waitcnt vmcnt(3)" ::: "memory");
    } else {
      asm volatile("s_waitcnt vmcnt(0)" ::: "memory");
    }
    __builtin_amdgcn_s_barrier();
    asm volatile("" ::: "memory");
  }

  // epilogue: C/D row=(lane>>4)*4+j, col=lane&15
#pragma unroll
  for (int mi = 0; mi < MI; ++mi)
#pragma unroll
    for (int nj = 0; nj < NJ; ++nj)
#pragma unroll
      for (int j = 0; j < 4; ++j) {
        int row = bm + wr * PM + mi * 16 + g * 4 + j;
        int col = bn + wc * PN + nj * 16 + r;
        C[(size_t)row * N + col] = (OutT)acc[mi][nj][j];
      }
}

// ---------------------------------------------------------------- flash attention, split-KV x4, LDS-staged K/V
// grid = 2048 four-wave blocks: kvh = bx&7 (XCD affinity), s = (bx>>3)&3 (KV
// quarter), qblk = 63 - (bx>>5) (heavy-first -> LPT dynamic balance).
// TRIPLE-buffered LDS, stage issued TWO tiles ahead, counted s_waitcnt
// vmcnt(4) + raw s_barrier (T4: never drain to 0 in the main loop) --
// stage(t+2) stays in flight across the barrier; only stage(t+1) must land.
// K LDS: half-row geometry [kvrow*2+h][chunk ^ (kvrow&7)] (zero-conflict).
// V: two 32-elem d-rows packed per 128B pseudo-row. Sources inverse-swizzled.
// Swapped QK^T (mfma(K,Q) -> S^T), per-lane softmax in exp2 domain (in-place).
__global__ __launch_bounds__(256) void attn_kernel(const bf16* __restrict__ QKV,
                                                   const bf16* __restrict__ Vt,
                                                   bf16* __restrict__ Opart,
                                                   float* __restrict__ Mpart,
                                                   float* __restrict__ Lpart) {
  __shared__ bf16 Kl[3][32 * 128];   // [kvrow*2+h][pos^(kvrow&7)] 64-elem half-rows
  __shared__ bf16 Vl[3][128 * 32];   // [d>>1][((d&1)*4+c)^((d>>1)&7)] pseudo-rows
  const int tid = threadIdx.x;
  const int w = tid >> 6, lane = tid & 63;
  const int l31 = lane & 31, hi = lane >> 5;
  const int bx = blockIdx.x;
  const int kvh = bx & 7;
  const int rest = bx >> 3;
  const int s = rest & 3;
  const int qblk = 63 - (rest >> 2);
  const int h = kvh * 4 + w;
  const int q0 = qblk * 32;
  const int pid = (h * 64 + qblk) * NSPLIT + s;
  const float scale = 0.12751746f;   // (1/sqrt(128)) * log2(e) -> exp2-domain

  const int nt = qblk + 1;                 // total KV tiles for this q-block
  const int t0 = (nt * s) >> 2;            // this split's tile range
  const int t1 = (nt * (s + 1)) >> 2;

  f32x16 o[4];
#pragma unroll
  for (int t = 0; t < 4; ++t)
#pragma unroll
    for (int r = 0; r < 16; ++r) o[t][r] = 0.f;
  float m_run = -1e30f, l_run = 0.f;

  auto stage = [&](int bufi, int kv0) {   // 4 gload_lds per wave (2 K + 2 V)
#pragma unroll
    for (int ii = 0; ii < 2; ++ii) {
      int ins = w * 2 + ii;  // 8 x 1KB instrs each for K and V, split over 4 waves
      int hr = ins * 8 + (lane >> 3);                 // K half-row index
      int kvrow = hr >> 1, hK = hr & 1;
      int gk = ((lane & 7) ^ (kvrow & 7)) + 8 * hK;   // inverse chunk swizzle
      gload_lds16(&QKV[(size_t)(kv0 + kvrow) * QKVN + KOFF + kvh * DHEAD + gk * 8],
                  &Kl[bufi][ins * 512]);
      int pr = ins * 8 + (lane >> 3);                 // V pseudo-row index
      int xv = (lane & 7) ^ (pr & 7);
      int dV = pr * 2 + (xv >> 2);
      gload_lds16(&Vt[(size_t)(kvh * DHEAD + dV) * S_LEN + kv0 + (xv & 3) * 8],
                  &Vl[bufi][ins * 512]);
    }
  };

  if (t0 < t1) {
    // Q B-fragments, pre-scaled: B col=lane&31=q, k=hi*8+j (per 16-k chunk)
    bf16x8 qf[8];
#pragma unroll
    for (int k8 = 0; k8 < 8; ++k8) {
      bf16x8 raw = *(const bf16x8*)&QKV[(size_t)(q0 + l31) * QKVN + h * DHEAD + k8 * 16 + hi * 8];
#pragma unroll
      for (int e = 0; e < 8; ++e) qf[k8][e] = (bf16)((float)raw[e] * scale);
    }

    // ---- prologue: stage t0 (and t0+1), wait only for t0, barrier
    int cur = t0 % 3;
    stage(cur, t0 * 32);
    if (t0 + 1 < t1) {
      stage(cur == 2 ? 0 : cur + 1, (t0 + 1) * 32);
      asm volatile("s_waitcnt vmcnt(4)" ::: "memory");   // t0 landed, t0+1 in flight
    } else {
      asm volatile("s_waitcnt vmcnt(0)" ::: "memory");
    }
    __builtin_amdgcn_s_barrier();
    asm volatile("" ::: "memory");

    for (int t = t0; t < t1; ++t) {
      if (t + 2 < t1) {                    // stage two ahead into buf (cur+2)%3
        int s2 = cur ? cur - 1 : 2;
        stage(s2, (t + 2) * 32);
      }

      // ---- QK^T (swapped): st[reg] = S^T[kv(reg,hi)][q=lane&31]
      f32x16 st;
#pragma unroll
      for (int r = 0; r < 16; ++r) st[r] = 0.f;
      __builtin_amdgcn_s_setprio(1);
#pragma unroll
      for (int k8 = 0; k8 < 8; ++k8) {
        int g = 2 * k8 + hi;
        bf16x8 kf = *(const bf16x8*)&Kl[cur][l31 * 128 + (g >> 3) * 64 +
                                             (((g & 7) ^ (l31 & 7)) << 3)];
        st = __builtin_amdgcn_mfma_f32_32x32x16_bf16(kf, qf[k8], st, 0, 0, 0);
      }
      __builtin_amdgcn_s_setprio(0);

      if (t == nt - 1) {  // causal mask: only the diagonal tile
#pragma unroll
        for (int r = 0; r < 16; ++r) {
          int kvr = (r & 3) + 8 * (r >> 2) + 4 * hi;
          if (kvr > l31) st[r] = -1e30f;
        }
      }
      // ---- per-lane online softmax (exp2 domain, in-place st -> p)
      float pmax = st[0];
#pragma unroll
      for (int r = 1; r < 16; ++r) pmax = fmaxf(pmax, st[r]);
      pmax = fmaxf(pmax, __shfl_xor(pmax, 32));
      if (!__all(pmax - m_run <= 8.0f)) {  // T13 defer-max
        float mnew = fmaxf(m_run, pmax);
        float corr = exp2f(m_run - mnew);
        m_run = mnew;
        l_run *= corr;
#pragma unroll
        for (int r = 0; r < 16; ++r) {
          float cr = __shfl(corr, (r & 3) + 8 * (r >> 2) + 4 * hi);
          o[0][r] *= cr; o[1][r] *= cr; o[2][r] *= cr; o[3][r] *= cr;
        }
      }
      float rs = 0.f;
#pragma unroll
      for (int r = 0; r < 16; ++r) { st[r] = exp2f(st[r] - m_run); rs += st[r]; }
      rs += __shfl_xor(rs, 32);
      l_run += rs;
      // ---- repack P into PV A-frags (two independent halves, low reg pressure)
      bf16x8 pf0, pf1;
      {
        unsigned int A0[4], X0[4];
#pragma unroll
        for (int j = 0; j < 4; ++j) {
          unsigned short lo = __builtin_bit_cast(unsigned short, (bf16)st[2 * j]);
          unsigned short hi16 = __builtin_bit_cast(unsigned short, (bf16)st[2 * j + 1]);
          A0[j] = (unsigned int)lo | ((unsigned int)hi16 << 16);
        }
#pragma unroll
        for (int j = 0; j < 4; ++j) X0[j] = __shfl_xor(A0[j], 32);
        uint4v w0v = {hi ? X0[2] : A0[0], hi ? X0[3] : A0[1],
                      hi ? A0[2] : X0[0], hi ? A0[3] : X0[1]};
        pf0 = __builtin_bit_cast(bf16x8, w0v);
      }
      {
        unsigned int A1[4], X1[4];
#pragma unroll
        for (int j = 0; j < 4; ++j) {
          unsigned short lo = __builtin_bit_cast(unsigned short, (bf16)st[8 + 2 * j]);
          unsigned short hi16 = __builtin_bit_cast(unsigned short, (bf16)st[9 + 2 * j]);
          A1[j] = (unsigned int)lo | ((unsigned int)hi16 << 16);
        }
#pragma unroll
        for (int j = 0; j < 4; ++j) X1[j] = __shfl_xor(A1[j], 32);
        uint4v w1v = {hi ? X1[2] : A1[0], hi ? X1[3] : A1[1],
                      hi ? A1[2] : X1[0], hi ? A1[3] : X1[1]};
        pf1 = __builtin_bit_cast(bf16x8, w1v);
      }
      // ---- PV: O[q, d] += P * V (V frags from LDS, pseudo-row swizzle)
      __builtin_amdgcn_s_setprio(1);
#pragma unroll
      for (int tt = 0; tt < 4; ++tt) {
        int pr = tt * 16 + (l31 >> 1);
        int sb4 = (l31 & 1) << 2;
        bf16x8 v0 = *(const bf16x8*)&Vl[cur][pr * 64 + (((sb4 + hi) ^ (pr & 7)) << 3)];
        bf16x8 v1 = *(const bf16x8*)&Vl[cur][pr * 64 + (((sb4 + 2 + hi) ^ (pr & 7)) << 3)];
        o[tt] = __builtin_amdgcn_mfma_f32_32x32x16_bf16(pf0, v0, o[tt], 0, 0, 0);
        o[tt] = __builtin_amdgcn_mfma_f32_32x32x16_bf16(pf1, v1, o[tt], 0, 0, 0);
      }
      __builtin_amdgcn_s_setprio(0);

      // ---- counted wait: stage(t+1) must have landed; stage(t+2) stays in flight
      if (t + 2 < t1) {
        asm volatile("s_waitcnt vmcnt(4)" ::: "memory");
      } else {
        asm volatile("s_waitcnt vmcnt(0)" ::: "memory");
      }
      __builtin_amdgcn_s_barrier();
      asm volatile("" ::: "memory");
      cur = (cur == 2) ? 0 : cur + 1;
    }
  }

  // partial epilogue: normalize by l (0 if empty), store bf16 O + per-row m,l
  float linv = (l_run > 0.f) ? 1.0f / l_run : 0.f;
  if (hi == 0) {
    Mpart[pid * 32 + l31] = m_run;
    Lpart[pid * 32 + l31] = l_run;
  }
#pragma unroll
  for (int r = 0; r < 16; ++r) {
    int qloc = (r & 3) + 8 * (r >> 2) + 4 * hi;
    float li = __shfl(linv, qloc);
    size_t row = (size_t)pid * (32 * DHEAD) + (size_t)qloc * DHEAD;
#pragma unroll
    for (int t2 = 0; t2 < 4; ++t2)
      Opart[row + t2 * 32 + l31] = (bf16)(o[t2][r] * li);
  }
}

// ---------------------------------------------------------------- merge split-KV partials (4-way)
// grid = 2048 (h*64+qblk), 256 threads: thread -> (row r = tid>>3, 16-col seg).
__global__ __launch_bounds__(256) void attn_merge(const bf16* __restrict__ Opart,
                                                  const float* __restrict__ Mpart,
                                                  const float* __restrict__ Lpart,
                                                  bf16* __restrict__ Oout) {
  const int bx = blockIdx.x;
  const int h = bx >> 6, qblk = bx & 63;
  const int tid = threadIdx.x;
  const int r = tid >> 3, cseg = (tid & 7) * 16;
  const int pid0 = bx * NSPLIT;
  float m[NSPLIT], l[NSPLIT];
  float M = -1e30f;
#pragma unroll
  for (int s = 0; s < NSPLIT; ++s) {
    m[s] = Mpart[(pid0 + s) * 32 + r];
    l[s] = Lpart[(pid0 + s) * 32 + r];
    M = fmaxf(M, m[s]);
  }
  float wsum = 0.f, wv[NSPLIT];
#pragma unroll
  for (int s = 0; s < NSPLIT; ++s) { wv[s] = l[s] * exp2f(m[s] - M); wsum += wv[s]; }
  float inv = 1.0f / wsum;
#pragma unroll
  for (int s = 0; s < NSPLIT; ++s) wv[s] *= inv;
  size_t dst = (size_t)(qblk * 32 + r) * HDIM + h * DHEAD + cseg;
#pragma unroll
  for (int half = 0; half < 2; ++half) {
    float acc[8];
#pragma unroll
    for (int e = 0; e < 8; ++e) acc[e] = 0.f;
#pragma unroll
    for (int s = 0; s < NSPLIT; ++s) {
      bf16x8 a = *(const bf16x8*)&Opart[(size_t)(pid0 + s) * (32 * DHEAD) +
                                        (size_t)r * DHEAD + cseg + half * 8];
#pragma unroll
      for (int e = 0; e < 8; ++e) acc[e] += wv[s] * (float)a[e];
    }
    bf16x8 out;
#pragma unroll
    for (int e = 0; e < 8; ++e) out[e] = (bf16)acc[e];
    *(bf16x8*)&Oout[dst + half * 8] = out;
  }
}

// ---------------------------------------------------------------- launcher
extern "C" void kernel_launch(void* const* d_in, const int* in_sizes, int n_in,
                              void* d_out, int out_size, void* d_ws, size_t ws_size,
                              hipStream_t stream) {
  const float* X   = (const float*)d_in[0];
  const int*   pos = (const int*)d_in[1];
  const float* Wq  = (const float*)d_in[2];
  const float* Wk  = (const float*)d_in[3];
  const float* Wv  = (const float*)d_in[4];
  const float* Wo  = (const float*)d_in[5];
  float* out = (float*)d_out;
  char* ws = (char*)d_ws;

  size_t off = 0;
  bf16* Xb    = (bf16*)(ws + off); off += (size_t)2048 * 4096 * 2;
  bf16* Wqkvb = (bf16*)(ws + off); off += (size_t)6144 * 4096 * 2;
  bf16* Wob   = (bf16*)(ws + off); off += (size_t)4096 * 4096 * 2;
  bf16* QKV   = (bf16*)(ws + off); off += (size_t)2048 * 6144 * 2;
  bf16* Vt    = (bf16*)(ws + off); off += (size_t)1024 * 2048 * 2;
  bf16* attnb = (bf16*)(ws + off); off += (size_t)2048 * 4096 * 2;
  float* tab  = (float*)(ws + off); off += (size_t)2048 * 64 * 2 * 4;
  float* Mpart = (float*)(ws + off); off += (size_t)8192 * 32 * 4;
  float* Lpart = (float*)(ws + off); off += (size_t)8192 * 32 * 4;

  // split-KV x4 partials (8192 x 32 x 128 bf16 = 67.1 MB) alias Xb+Wqkvb
  // exactly (8192*4096 == 2048*4096 + 6144*4096); both dead after QKV GEMM.
  bf16* Opart = (bf16*)Xb;

  cvt_f32_bf16<<<2048 * 4096 / 4 / 256, 256, 0, stream>>>(X, Xb, 2048 * 4096 / 4);
  cvt_f32_bf16<<<4096 * 4096 / 4 / 256, 256, 0, stream>>>(Wq, Wqkvb, 4096 * 4096 / 4);
  cvt_f32_bf16<<<1024 * 4096 / 4 / 256, 256, 0, stream>>>(Wk, Wqkvb + (size_t)4096 * 4096,
                                                          1024 * 4096 / 4);
  cvt_f32_bf16<<<1024 * 4096 / 4 / 256, 256, 0, stream>>>(Wv, Wqkvb + (size_t)5120 * 4096,
                                                          1024 * 4096 / 4);
  cvt_f32_bf16<<<4096 * 4096 / 4 / 256, 256, 0, stream>>>(Wo, Wob, 4096 * 4096 / 4);
  rope_table<<<2048 * 64 / 256, 256, 0, stream>>>(pos, tab);
  // QKV proj: M=2048 (8 tiles of 256), N=6144 (24 tiles of 256) -> 192 blocks
  gemm8p<bf16, 256, 256, 2, 4, 4, 6, 4><<<192, 512, 0, stream>>>(Xb, Wqkvb, QKV,
                                                                 2048, QKVN, 4096);
  rope_apply<<<2048 * 40 * 64 / 256, 256, 0, stream>>>(QKV, tab);
  transpose_v<<<dim3(2048 / 64, 1024 / 64), 256, 0, stream>>>(QKV, Vt);
  attn_kernel<<<2048, 256, 0, stream>>>(QKV, Vt, Opart, Mpart, Lpart);
  attn_merge<<<2048, 256, 0, stream>>>(Opart, Mpart, Lpart, attnb);
  // out proj: M=2048 (8 tiles of 256), N=4096 (32 tiles of 128) -> 256 blocks
  gemm8p<float, 256, 128, 4, 2, 4, 8, 4><<<256, 512, 0, stream>>>(attnb, Wob, out,
                                                                  2048, 4096, 4096);
}

// Round 12
// 371.537 us; speedup vs baseline: 1.2524x; 1.2524x over previous
//
#include <hip/hip_runtime.h>
#include <hip/hip_bf16.h>
#include <stdint.h>

typedef __bf16 bf16;
typedef __attribute__((ext_vector_type(8))) __bf16 bf16x8;
typedef __attribute__((ext_vector_type(4))) __bf16 bf16x4;
typedef __attribute__((ext_vector_type(4))) float f32x4;
typedef __attribute__((ext_vector_type(16))) float f32x16;
typedef __attribute__((ext_vector_type(4))) unsigned int uint4v;

#define S_LEN 2048
#define HDIM  4096
#define NQH   32
#define NKVH  8
#define DHEAD 128
#define QKVN  6144   /* 4096 Q + 1024 K + 1024 V */
#define KOFF  4096
#define VOFF  5120
#define NSPLIT 4

__device__ __forceinline__ void gload_lds16(const bf16* g, bf16* l) {
  __builtin_amdgcn_global_load_lds(
      (const __attribute__((address_space(1))) unsigned int*)g,
      (__attribute__((address_space(3))) unsigned int*)l, 16, 0, 0);
}

// ---------------------------------------------------------------- f32 -> bf16
__global__ __launch_bounds__(256) void cvt_f32_bf16(const float* __restrict__ in,
                                                    bf16* __restrict__ out, int n4) {
  int i = blockIdx.x * 256 + threadIdx.x;
  if (i >= n4) return;
  float4 v = ((const float4*)in)[i];
  bf16x4 ov = {(bf16)v.x, (bf16)v.y, (bf16)v.z, (bf16)v.w};
  *(bf16x4*)&out[(size_t)i * 4] = ov;
}

// ---------------------------------------------------------------- RoPE table
__global__ __launch_bounds__(256) void rope_table(const int* __restrict__ pos,
                                                  float* __restrict__ tab) {
  int idx = blockIdx.x * 256 + threadIdx.x;  // 2048*64
  int i = idx & 63, s = idx >> 6;
  float p = (float)pos[s];
  float invf = powf(10000.0f, -(float)i * (1.0f / 64.0f));
  float ang = p * invf;
  tab[idx * 2]     = cosf(ang);
  tab[idx * 2 + 1] = sinf(ang);
}

// ---------------------------------------------------------------- RoPE apply (in-place on Q,K cols of QKV)
__global__ __launch_bounds__(256) void rope_apply(bf16* __restrict__ QKV,
                                                  const float* __restrict__ tab) {
  int idx = blockIdx.x * 256 + threadIdx.x;  // 2048*40*64
  int dp = idx & 63;
  int t = idx >> 6;
  int head = t % 40;          // 0..31 = Q heads, 32..39 = K heads
  int s = t / 40;
  float c  = tab[(s * 64 + dp) * 2];
  float sn = tab[(s * 64 + dp) * 2 + 1];
  size_t base = (size_t)s * QKVN + head * DHEAD;
  float x0 = (float)QKV[base + dp];
  float x1 = (float)QKV[base + 64 + dp];
  QKV[base + dp]      = (bf16)(x0 * c - x1 * sn);
  QKV[base + 64 + dp] = (bf16)(x1 * c + x0 * sn);
}

// ---------------------------------------------------------------- V transpose: QKV V-cols -> Vt[kvh*128+d][s]
__global__ __launch_bounds__(256) void transpose_v(const bf16* __restrict__ QKV,
                                                   bf16* __restrict__ Vt) {
  __shared__ bf16 t[64][72];
  int tid = threadIdx.x;
  int bs = blockIdx.x * 64, bc = blockIdx.y * 64;
  int sl = tid >> 3, cb = (tid & 7) * 8;
#pragma unroll
  for (int ss = 0; ss < 64; ss += 32) {
    int s = sl + ss;
    *(bf16x8*)&t[s][cb] = *(const bf16x8*)&QKV[(size_t)(bs + s) * QKVN + VOFF + bc + cb];
  }
  __syncthreads();
  int cl = tid >> 3, sb = (tid & 7) * 8;
#pragma unroll
  for (int cc = 0; cc < 64; cc += 32) {
    int c = cl + cc;
    bf16x8 v;
#pragma unroll
    for (int k = 0; k < 8; ++k) v[k] = t[sb + k][c];
    *(bf16x8*)&Vt[(size_t)(bc + c) * S_LEN + bs + sb] = v;
  }
}

// ---------------------------------------------------------------- GEMM phase-split: C[M,N] = A[M,K]*B[N,K]^T
// BM=128, BK=64, 8 waves (2x4), grid = EXACTLY 256 blocks (16x16 tiles,
// 1/CU, zero dispatch tail). A TRIPLE-buffered (staged 2 tiles ahead),
// B DOUBLE-buffered (staged across phases 0-2 of the previous tile) ->
// end-of-tile counted s_waitcnt vmcnt(2): A(t+2)'s 2 instrs stay in flight,
// everything tile t+1 needs is confirmed landed. NEVER drains to 0 in
// steady state (T4). 4 phases/tile (ks x nj-half), each {ds_read frags ||
// stage slice -> s_barrier -> lgkmcnt(0) -> setprio(1) MFMA setprio(0) ->
// s_barrier} (T3+T5). LDS: 128B rows, 8 chunks ^ (row&7) -- the PROVEN
// zero-conflict geometry (T2, G21 both-sides; round-11's BK=32 64B rows
// aliased banks). Compact per-XCD mapping: XCD owns 2 col-stripes x 16 rows.
template <typename OutT, int BN>
__global__ __launch_bounds__(512, 2) void gemm_ph(const bf16* __restrict__ A,
                                                  const bf16* __restrict__ B,
                                                  OutT* __restrict__ C,
                                                  int M, int N, int K) {
  constexpr int NJ = BN / 64;        // 6 (BN=384) or 4 (BN=256)
  constexpr int NJH = NJ / 2;        // per-phase nj count
  constexpr int LB = BN / 64;        // B gload instrs per wave per tile
  constexpr int WCW = BN / 4;        // per-wave N width
  __shared__ bf16 Al[3][128 * 64];
  __shared__ bf16 Bl[2][BN * 64];
  const int tid = threadIdx.x;
  const int w = tid >> 6, lane = tid & 63;
  const int r = lane & 15, g = lane >> 4;
  const int wr = w >> 2, wc = w & 3;
  const int id = blockIdx.x;
  const int xcd = id & 7, o = id >> 3;     // dispatch round-robins id%8 -> XCD
  const int by = o >> 1, bx = xcd * 2 + (o & 1);   // XCD owns 2 col-stripes
  const int bm = by * 128, bn = bx * BN;

  f32x4 acc[4][NJ];
#pragma unroll
  for (int mi = 0; mi < 4; ++mi)
#pragma unroll
    for (int nj = 0; nj < NJ; ++nj) acc[mi][nj] = (f32x4){0.f, 0.f, 0.f, 0.f};

  auto stageA = [&](int slot, int k0) {    // 2 instrs/wave
#pragma unroll
    for (int j = 0; j < 2; ++j) {
      int chunk = (j * 8 + w) * 64 + lane;
      int row = chunk >> 3, c = chunk & 7;
      gload_lds16(&A[(size_t)(bm + row) * K + k0 + ((c ^ (row & 7)) << 3)],
                  &Al[slot][(j * 8 + w) * 512]);
    }
  };
  auto stageB = [&](int buf, int k0, int i0, int i1) {
#pragma unroll
    for (int i = 0; i < LB; ++i) {
      if (i < i0 || i >= i1) continue;
      int chunk = (i * 8 + w) * 64 + lane;
      int row = chunk >> 3, c = chunk & 7;
      gload_lds16(&B[(size_t)(bn + row) * K + k0 + ((c ^ (row & 7)) << 3)],
                  &Bl[buf][(i * 8 + w) * 512]);
    }
  };

  const int NT = K >> 6;
  // prologue: A(0), B(0), A(1); counted wait leaves A(1) in flight
  stageA(0, 0);
  stageB(0, 0, 0, LB);
  stageA(1, 64);
  asm volatile("s_waitcnt vmcnt(2)" ::: "memory");
  __builtin_amdgcn_s_barrier();
  asm volatile("" ::: "memory");

  for (int t = 0; t < NT; ++t) {
    const bf16* Ac = Al[t % 3];
    const bf16* Bc = Bl[t & 1];
    const bool p1 = (t + 1 < NT), p2 = (t + 2 < NT);
    const int kn = (t + 1) << 6;
    bf16x8 af[4], bfr[NJH];

#pragma unroll
    for (int p = 0; p < 4; ++p) {
      const int ks = p >> 1, njh = p & 1;
      // ds_read fragments for this phase
      if (njh == 0) {
#pragma unroll
        for (int mi = 0; mi < 4; ++mi) {
          int row = wr * 64 + mi * 16 + r;
          af[mi] = *(const bf16x8*)&Ac[row * 64 + (((ks * 4 + g) ^ (row & 7)) << 3)];
        }
      }
#pragma unroll
      for (int nj = 0; nj < NJH; ++nj) {
        int row = wc * WCW + (njh * NJH + nj) * 16 + r;
        bfr[nj] = *(const bf16x8*)&Bc[row * 64 + (((ks * 4 + g) ^ (row & 7)) << 3)];
      }
      // stage slice (B of t+1 over phases 0-2; A of t+2 at phase 3)
      if (p == 0 && p1) stageB((t + 1) & 1, kn, 0, 2);
      if (p == 1 && p1) stageB((t + 1) & 1, kn, 2, 4);
      if (p == 2 && p1) stageB((t + 1) & 1, kn, 4, LB);   // no-op when LB==4
      if (p == 3 && p2) stageA((t + 2) % 3, (t + 2) << 6);
      __builtin_amdgcn_s_barrier();
      asm volatile("s_waitcnt lgkmcnt(0)" ::: "memory");
      __builtin_amdgcn_s_setprio(1);
#pragma unroll
      for (int mi = 0; mi < 4; ++mi)
#pragma unroll
        for (int nj = 0; nj < NJH; ++nj)
          acc[mi][njh * NJH + nj] = __builtin_amdgcn_mfma_f32_16x16x32_bf16(
              af[mi], bfr[nj], acc[mi][njh * NJH + nj], 0, 0, 0);
      __builtin_amdgcn_s_setprio(0);
      __builtin_amdgcn_s_barrier();
      asm volatile("" ::: "memory");
    }
    // end of tile: A(t+1)+B(t+1) confirmed; A(t+2) stays in flight
    if (p2) asm volatile("s_waitcnt vmcnt(2)" ::: "memory");
    else    asm volatile("s_waitcnt vmcnt(0)" ::: "memory");
    __builtin_amdgcn_s_barrier();
    asm volatile("" ::: "memory");
  }

  // epilogue: C/D row=(lane>>4)*4+j, col=lane&15
#pragma unroll
  for (int mi = 0; mi < 4; ++mi)
#pragma unroll
    for (int nj = 0; nj < NJ; ++nj)
#pragma unroll
      for (int j = 0; j < 4; ++j) {
        int row = bm + wr * 64 + mi * 16 + g * 4 + j;
        int col = bn + wc * WCW + nj * 16 + r;
        C[(size_t)row * N + col] = (OutT)acc[mi][nj][j];
      }
}

// ---------------------------------------------------------------- flash attention, split-KV x4, LDS-staged K/V
// grid = 2048 four-wave blocks: kvh = bx&7 (XCD affinity), s = (bx>>3)&3 (KV
// quarter), qblk = 63 - (bx>>5) (heavy-first -> LPT dynamic balance).
// TRIPLE-buffered LDS, stage issued TWO tiles ahead, counted s_waitcnt
// vmcnt(4) + raw s_barrier (T4: never drain to 0 in the main loop) --
// stage(t+2) stays in flight across the barrier; only stage(t+1) must land.
// K LDS: half-row geometry [kvrow*2+h][chunk ^ (kvrow&7)] (zero-conflict).
// V: two 32-elem d-rows packed per 128B pseudo-row. Sources inverse-swizzled.
// Swapped QK^T (mfma(K,Q) -> S^T), per-lane softmax in exp2 domain (in-place).
__global__ __launch_bounds__(256) void attn_kernel(const bf16* __restrict__ QKV,
                                                   const bf16* __restrict__ Vt,
                                                   bf16* __restrict__ Opart,
                                                   float* __restrict__ Mpart,
                                                   float* __restrict__ Lpart) {
  __shared__ bf16 Kl[3][32 * 128];   // [kvrow*2+h][pos^(kvrow&7)] 64-elem half-rows
  __shared__ bf16 Vl[3][128 * 32];   // [d>>1][((d&1)*4+c)^((d>>1)&7)] pseudo-rows
  const int tid = threadIdx.x;
  const int w = tid >> 6, lane = tid & 63;
  const int l31 = lane & 31, hi = lane >> 5;
  const int bx = blockIdx.x;
  const int kvh = bx & 7;
  const int rest = bx >> 3;
  const int s = rest & 3;
  const int qblk = 63 - (rest >> 2);
  const int h = kvh * 4 + w;
  const int q0 = qblk * 32;
  const int pid = (h * 64 + qblk) * NSPLIT + s;
  const float scale = 0.12751746f;   // (1/sqrt(128)) * log2(e) -> exp2-domain

  const int nt = qblk + 1;                 // total KV tiles for this q-block
  const int t0 = (nt * s) >> 2;            // this split's tile range
  const int t1 = (nt * (s + 1)) >> 2;

  f32x16 o[4];
#pragma unroll
  for (int t = 0; t < 4; ++t)
#pragma unroll
    for (int r = 0; r < 16; ++r) o[t][r] = 0.f;
  float m_run = -1e30f, l_run = 0.f;

  auto stage = [&](int bufi, int kv0) {   // 4 gload_lds per wave (2 K + 2 V)
#pragma unroll
    for (int ii = 0; ii < 2; ++ii) {
      int ins = w * 2 + ii;  // 8 x 1KB instrs each for K and V, split over 4 waves
      int hr = ins * 8 + (lane >> 3);                 // K half-row index
      int kvrow = hr >> 1, hK = hr & 1;
      int gk = ((lane & 7) ^ (kvrow & 7)) + 8 * hK;   // inverse chunk swizzle
      gload_lds16(&QKV[(size_t)(kv0 + kvrow) * QKVN + KOFF + kvh * DHEAD + gk * 8],
                  &Kl[bufi][ins * 512]);
      int pr = ins * 8 + (lane >> 3);                 // V pseudo-row index
      int xv = (lane & 7) ^ (pr & 7);
      int dV = pr * 2 + (xv >> 2);
      gload_lds16(&Vt[(size_t)(kvh * DHEAD + dV) * S_LEN + kv0 + (xv & 3) * 8],
                  &Vl[bufi][ins * 512]);
    }
  };

  if (t0 < t1) {
    // Q B-fragments, pre-scaled: B col=lane&31=q, k=hi*8+j (per 16-k chunk)
    bf16x8 qf[8];
#pragma unroll
    for (int k8 = 0; k8 < 8; ++k8) {
      bf16x8 raw = *(const bf16x8*)&QKV[(size_t)(q0 + l31) * QKVN + h * DHEAD + k8 * 16 + hi * 8];
#pragma unroll
      for (int e = 0; e < 8; ++e) qf[k8][e] = (bf16)((float)raw[e] * scale);
    }

    // ---- prologue: stage t0 (and t0+1), wait only for t0, barrier
    int cur = t0 % 3;
    stage(cur, t0 * 32);
    if (t0 + 1 < t1) {
      stage(cur == 2 ? 0 : cur + 1, (t0 + 1) * 32);
      asm volatile("s_waitcnt vmcnt(4)" ::: "memory");   // t0 landed, t0+1 in flight
    } else {
      asm volatile("s_waitcnt vmcnt(0)" ::: "memory");
    }
    __builtin_amdgcn_s_barrier();
    asm volatile("" ::: "memory");

    for (int t = t0; t < t1; ++t) {
      if (t + 2 < t1) {                    // stage two ahead into buf (cur+2)%3
        int s2 = cur ? cur - 1 : 2;
        stage(s2, (t + 2) * 32);
      }

      // ---- QK^T (swapped): st[reg] = S^T[kv(reg,hi)][q=lane&31]
      f32x16 st;
#pragma unroll
      for (int r = 0; r < 16; ++r) st[r] = 0.f;
      __builtin_amdgcn_s_setprio(1);
#pragma unroll
      for (int k8 = 0; k8 < 8; ++k8) {
        int g = 2 * k8 + hi;
        bf16x8 kf = *(const bf16x8*)&Kl[cur][l31 * 128 + (g >> 3) * 64 +
                                             (((g & 7) ^ (l31 & 7)) << 3)];
        st = __builtin_amdgcn_mfma_f32_32x32x16_bf16(kf, qf[k8], st, 0, 0, 0);
      }
      __builtin_amdgcn_s_setprio(0);

      if (t == nt - 1) {  // causal mask: only the diagonal tile
#pragma unroll
        for (int r = 0; r < 16; ++r) {
          int kvr = (r & 3) + 8 * (r >> 2) + 4 * hi;
          if (kvr > l31) st[r] = -1e30f;
        }
      }
      // ---- per-lane online softmax (exp2 domain, in-place st -> p)
      float pmax = st[0];
#pragma unroll
      for (int r = 1; r < 16; ++r) pmax = fmaxf(pmax, st[r]);
      pmax = fmaxf(pmax, __shfl_xor(pmax, 32));
      if (!__all(pmax - m_run <= 8.0f)) {  // T13 defer-max
        float mnew = fmaxf(m_run, pmax);
        float corr = exp2f(m_run - mnew);
        m_run = mnew;
        l_run *= corr;
#pragma unroll
        for (int r = 0; r < 16; ++r) {
          float cr = __shfl(corr, (r & 3) + 8 * (r >> 2) + 4 * hi);
          o[0][r] *= cr; o[1][r] *= cr; o[2][r] *= cr; o[3][r] *= cr;
        }
      }
      float rs = 0.f;
#pragma unroll
      for (int r = 0; r < 16; ++r) { st[r] = exp2f(st[r] - m_run); rs += st[r]; }
      rs += __shfl_xor(rs, 32);
      l_run += rs;
      // ---- repack P into PV A-frags (two independent halves, low reg pressure)
      bf16x8 pf0, pf1;
      {
        unsigned int A0[4], X0[4];
#pragma unroll
        for (int j = 0; j < 4; ++j) {
          unsigned short lo = __builtin_bit_cast(unsigned short, (bf16)st[2 * j]);
          unsigned short hi16 = __builtin_bit_cast(unsigned short, (bf16)st[2 * j + 1]);
          A0[j] = (unsigned int)lo | ((unsigned int)hi16 << 16);
        }
#pragma unroll
        for (int j = 0; j < 4; ++j) X0[j] = __shfl_xor(A0[j], 32);
        uint4v w0v = {hi ? X0[2] : A0[0], hi ? X0[3] : A0[1],
                      hi ? A0[2] : X0[0], hi ? A0[3] : X0[1]};
        pf0 = __builtin_bit_cast(bf16x8, w0v);
      }
      {
        unsigned int A1[4], X1[4];
#pragma unroll
        for (int j = 0; j < 4; ++j) {
          unsigned short lo = __builtin_bit_cast(unsigned short, (bf16)st[8 + 2 * j]);
          unsigned short hi16 = __builtin_bit_cast(unsigned short, (bf16)st[9 + 2 * j]);
          A1[j] = (unsigned int)lo | ((unsigned int)hi16 << 16);
        }
#pragma unroll
        for (int j = 0; j < 4; ++j) X1[j] = __shfl_xor(A1[j], 32);
        uint4v w1v = {hi ? X1[2] : A1[0], hi ? X1[3] : A1[1],
                      hi ? A1[2] : X1[0], hi ? A1[3] : X1[1]};
        pf1 = __builtin_bit_cast(bf16x8, w1v);
      }
      // ---- PV: O[q, d] += P * V (V frags from LDS, pseudo-row swizzle)
      __builtin_amdgcn_s_setprio(1);
#pragma unroll
      for (int tt = 0; tt < 4; ++tt) {
        int pr = tt * 16 + (l31 >> 1);
        int sb4 = (l31 & 1) << 2;
        bf16x8 v0 = *(const bf16x8*)&Vl[cur][pr * 64 + (((sb4 + hi) ^ (pr & 7)) << 3)];
        bf16x8 v1 = *(const bf16x8*)&Vl[cur][pr * 64 + (((sb4 + 2 + hi) ^ (pr & 7)) << 3)];
        o[tt] = __builtin_amdgcn_mfma_f32_32x32x16_bf16(pf0, v0, o[tt], 0, 0, 0);
        o[tt] = __builtin_amdgcn_mfma_f32_32x32x16_bf16(pf1, v1, o[tt], 0, 0, 0);
      }
      __builtin_amdgcn_s_setprio(0);

      // ---- counted wait: stage(t+1) must have landed; stage(t+2) stays in flight
      if (t + 2 < t1) {
        asm volatile("s_waitcnt vmcnt(4)" ::: "memory");
      } else {
        asm volatile("s_waitcnt vmcnt(0)" ::: "memory");
      }
      __builtin_amdgcn_s_barrier();
      asm volatile("" ::: "memory");
      cur = (cur == 2) ? 0 : cur + 1;
    }
  }

  // partial epilogue: normalize by l (0 if empty), store bf16 O + per-row m,l
  float linv = (l_run > 0.f) ? 1.0f / l_run : 0.f;
  if (hi == 0) {
    Mpart[pid * 32 + l31] = m_run;
    Lpart[pid * 32 + l31] = l_run;
  }
#pragma unroll
  for (int r = 0; r < 16; ++r) {
    int qloc = (r & 3) + 8 * (r >> 2) + 4 * hi;
    float li = __shfl(linv, qloc);
    size_t row = (size_t)pid * (32 * DHEAD) + (size_t)qloc * DHEAD;
#pragma unroll
    for (int t2 = 0; t2 < 4; ++t2)
      Opart[row + t2 * 32 + l31] = (bf16)(o[t2][r] * li);
  }
}

// ---------------------------------------------------------------- merge split-KV partials (4-way)
// grid = 2048 (h*64+qblk), 256 threads: thread -> (row r = tid>>3, 16-col seg).
__global__ __launch_bounds__(256) void attn_merge(const bf16* __restrict__ Opart,
                                                  const float* __restrict__ Mpart,
                                                  const float* __restrict__ Lpart,
                                                  bf16* __restrict__ Oout) {
  const int bx = blockIdx.x;
  const int h = bx >> 6, qblk = bx & 63;
  const int tid = threadIdx.x;
  const int r = tid >> 3, cseg = (tid & 7) * 16;
  const int pid0 = bx * NSPLIT;
  float m[NSPLIT], l[NSPLIT];
  float M = -1e30f;
#pragma unroll
  for (int s = 0; s < NSPLIT; ++s) {
    m[s] = Mpart[(pid0 + s) * 32 + r];
    l[s] = Lpart[(pid0 + s) * 32 + r];
    M = fmaxf(M, m[s]);
  }
  float wsum = 0.f, wv[NSPLIT];
#pragma unroll
  for (int s = 0; s < NSPLIT; ++s) { wv[s] = l[s] * exp2f(m[s] - M); wsum += wv[s]; }
  float inv = 1.0f / wsum;
#pragma unroll
  for (int s = 0; s < NSPLIT; ++s) wv[s] *= inv;
  size_t dst = (size_t)(qblk * 32 + r) * HDIM + h * DHEAD + cseg;
#pragma unroll
  for (int half = 0; half < 2; ++half) {
    float acc[8];
#pragma unroll
    for (int e = 0; e < 8; ++e) acc[e] = 0.f;
#pragma unroll
    for (int s = 0; s < NSPLIT; ++s) {
      bf16x8 a = *(const bf16x8*)&Opart[(size_t)(pid0 + s) * (32 * DHEAD) +
                                        (size_t)r * DHEAD + cseg + half * 8];
#pragma unroll
      for (int e = 0; e < 8; ++e) acc[e] += wv[s] * (float)a[e];
    }
    bf16x8 out;
#pragma unroll
    for (int e = 0; e < 8; ++e) out[e] = (bf16)acc[e];
    *(bf16x8*)&Oout[dst + half * 8] = out;
  }
}

// ---------------------------------------------------------------- launcher
extern "C" void kernel_launch(void* const* d_in, const int* in_sizes, int n_in,
                              void* d_out, int out_size, void* d_ws, size_t ws_size,
                              hipStream_t stream) {
  const float* X   = (const float*)d_in[0];
  const int*   pos = (const int*)d_in[1];
  const float* Wq  = (const float*)d_in[2];
  const float* Wk  = (const float*)d_in[3];
  const float* Wv  = (const float*)d_in[4];
  const float* Wo  = (const float*)d_in[5];
  float* out = (float*)d_out;
  char* ws = (char*)d_ws;

  size_t off = 0;
  bf16* Xb    = (bf16*)(ws + off); off += (size_t)2048 * 4096 * 2;
  bf16* Wqkvb = (bf16*)(ws + off); off += (size_t)6144 * 4096 * 2;
  bf16* Wob   = (bf16*)(ws + off); off += (size_t)4096 * 4096 * 2;
  bf16* QKV   = (bf16*)(ws + off); off += (size_t)2048 * 6144 * 2;
  bf16* Vt    = (bf16*)(ws + off); off += (size_t)1024 * 2048 * 2;
  bf16* attnb = (bf16*)(ws + off); off += (size_t)2048 * 4096 * 2;
  float* tab  = (float*)(ws + off); off += (size_t)2048 * 64 * 2 * 4;
  float* Mpart = (float*)(ws + off); off += (size_t)8192 * 32 * 4;
  float* Lpart = (float*)(ws + off); off += (size_t)8192 * 32 * 4;

  // split-KV x4 partials (8192 x 32 x 128 bf16 = 67.1 MB) alias Xb+Wqkvb
  // exactly (8192*4096 == 2048*4096 + 6144*4096); both dead after QKV GEMM.
  bf16* Opart = (bf16*)Xb;

  cvt_f32_bf16<<<2048 * 4096 / 4 / 256, 256, 0, stream>>>(X, Xb, 2048 * 4096 / 4);
  cvt_f32_bf16<<<4096 * 4096 / 4 / 256, 256, 0, stream>>>(Wq, Wqkvb, 4096 * 4096 / 4);
  cvt_f32_bf16<<<1024 * 4096 / 4 / 256, 256, 0, stream>>>(Wk, Wqkvb + (size_t)4096 * 4096,
                                                          1024 * 4096 / 4);
  cvt_f32_bf16<<<1024 * 4096 / 4 / 256, 256, 0, stream>>>(Wv, Wqkvb + (size_t)5120 * 4096,
                                                          1024 * 4096 / 4);
  cvt_f32_bf16<<<4096 * 4096 / 4 / 256, 256, 0, stream>>>(Wo, Wob, 4096 * 4096 / 4);
  rope_table<<<2048 * 64 / 256, 256, 0, stream>>>(pos, tab);
  // QKV proj: 128x384 tiles -> 16x16 = 256 blocks (exactly 1/CU)
  gemm_ph<bf16, 384><<<256, 512, 0, stream>>>(Xb, Wqkvb, QKV, 2048, QKVN, 4096);
  rope_apply<<<2048 * 40 * 64 / 256, 256, 0, stream>>>(QKV, tab);
  transpose_v<<<dim3(2048 / 64, 1024 / 64), 256, 0, stream>>>(QKV, Vt);
  attn_kernel<<<2048, 256, 0, stream>>>(QKV, Vt, Opart, Mpart, Lpart);
  attn_merge<<<2048, 256, 0, stream>>>(Opart, Mpart, Lpart, attnb);
  // out proj: 128x256 tiles -> 16x16 = 256 blocks (exactly 1/CU)
  gemm_ph<float, 256><<<256, 512, 0, stream>>>(attnb, Wob, out, 2048, 4096, 4096);
}